// Round 1
// baseline (306.632 us; speedup 1.0000x reference)
//
#include <hip/hip_runtime.h>

// expRNN/modReLU recurrence, B=8192, T=784, I=1, H=30, C=10.
//
// Round 6: same L=8 rotation dataflow as R5 (verified), plus stall removal:
//   - VGPR_Count was 104 < the ~150 live floats required => allocator was
//     demoting wq (in-loop LDS remat or AGPR shuffles). Re-pin all 128 wq +
//     wih/bm INSIDE the t-loop (empty asm, 0 instructions) to force true
//     register residency across the loop body.
//   - t-loop unrolled x4 (196 outer iters): branch bubble + loop scalars /4.
//   - x staged as float4 ds_read_b128 once per 4 steps, double-buffered one
//     full body (~1600 cyc) ahead: no per-step lgkm waits. XPAD=788 -> each
//     batch row is 16B aligned (788*4 % 16 == 0).
//   - All 28 DPP rotations of a step issued as one cluster into pinned
//     q[7][4] before any fma: >=20 instr slack DPP->consumer (was 0-3).
// Issue model: 410 cyc/step; R5 measured 571 cyc/step (VALUBusy 71%).
// Target: kill the 165 stall cyc/step -> ~155-185 us.

#define T_STEPS 784
#define NBATCH  8192
#define NH      30
#define NC      10
#define BPB     8     // batches per block
#define XPAD    788   // padded x row: 788%4==0 (float4 LDS) and
                      // 788%32==20 -> 8 batch rows hit distinct banks

// lane receives value from lane (w - 2S) & 15 within its 16-lane row
#define ROR2(dst, src, S) \
    dst = __int_as_float(__builtin_amdgcn_update_dpp( \
        0, __float_as_int(src), 0x120 + 2*(S), 0xf, 0xf, true))

#define PIN8(a,b,c,d,e,f,g,h) \
    asm volatile("" : "+v"(a),"+v"(b),"+v"(c),"+v"(d), \
                      "+v"(e),"+v"(f),"+v"(g),"+v"(h))
#define PIN4(a,b,c,d) \
    asm volatile("" : "+v"(a),"+v"(b),"+v"(c),"+v"(d))

__global__ __launch_bounds__(64, 1)
void rnn_modrelu_l8(const float* __restrict__ inp,    // [B, T, 1]
                    const float* __restrict__ W_ih,   // [H, 1]
                    const float* __restrict__ W_hh,   // [H, H]
                    const float* __restrict__ b_mod,  // [H]
                    const float* __restrict__ W_lin,  // [C, H]
                    const float* __restrict__ b_lin,  // [C]
                    float* __restrict__ out)          // [B, C]
{
    __shared__ __align__(16) float xl[BPB * XPAD];   // 25.2 KB
    __shared__ __align__(16) float wl[NH * NH];      // 3.6 KB
    __shared__ float hfin[BPB * 32];

    const int l     = threadIdx.x;
    const int blk   = blockIdx.x;
    const int w16   = l & 15;
    const int row16 = l >> 4;
    const int u     = w16 >> 1;          // 8-lane sub-index (chunk owner)
    const int bl    = 2 * row16 + (w16 & 1);  // local batch 0..7

    // ---- preload x (8 batches x 784), padded rows, coalesced float4 ----
    {
        const float4* src = (const float4*)(inp + (size_t)blk * (BPB * T_STEPS));
        #pragma unroll
        for (int k = 0; k < 25; ++k) {
            int v = l + 64 * k;                 // float4 index, < 1568
            if (v < (BPB * T_STEPS) / 4) {
                int b   = v / 196;              // 196 float4 per batch row
                int rem = v - b * 196;
                *(float4*)(xl + b * XPAD + 4 * rem) = src[v];
            }
        }
    }
    // ---- stage W_hh to LDS (coalesced) ----
    {
        const float4* src = (const float4*)W_hh;
        #pragma unroll
        for (int k = 0; k < 4; ++k) {
            int idx = l + 64 * k;
            if (idx < (NH * NH) / 4) ((float4*)wl)[idx] = src[idx];
        }
    }
    __syncthreads();

    // ---- per-lane pre-rotated W: step s consumes chunk c=(u-s)&7 ----
    const int r0 = 4 * u;                // first owned row
    float wq[8][4][4];
    #pragma unroll
    for (int s = 0; s < 8; ++s) {
        const int c = (u - s) & 7;
        #pragma unroll
        for (int r = 0; r < 4; ++r) {
            const int row = r0 + r;
            #pragma unroll
            for (int j = 0; j < 4; ++j) {
                const int col = 4 * c + j;
                wq[s][r][j] = (row < NH && col < NH) ? wl[row * NH + col] : 0.0f;
            }
        }
    }
    float wih[4], bm[4];
    #pragma unroll
    for (int r = 0; r < 4; ++r) {
        const int row = r0 + r;
        wih[r] = (row < NH) ? W_ih[row]  : 0.0f;
        bm[r]  = (row < NH) ? b_mod[row] : 0.0f;
    }
    // pin W in VGPRs (pre-loop)
    #pragma unroll
    for (int s = 0; s < 8; ++s) {
        PIN8(wq[s][0][0], wq[s][0][1], wq[s][0][2], wq[s][0][3],
             wq[s][1][0], wq[s][1][1], wq[s][1][2], wq[s][1][3]);
        PIN8(wq[s][2][0], wq[s][2][1], wq[s][2][2], wq[s][2][3],
             wq[s][3][0], wq[s][3][1], wq[s][3][2], wq[s][3][3]);
    }

    float h0 = 0.0f, h1 = 0.0f, h2 = 0.0f, h3 = 0.0f;  // own rows r0..r0+3

// one recurrence step; all 28 DPP rotations clustered & pinned up front
#define ROTS(S) ROR2(q[(S)-1][0], h0, S); ROR2(q[(S)-1][1], h1, S); \
                ROR2(q[(S)-1][2], h2, S); ROR2(q[(S)-1][3], h3, S)
#define FMAS(S) \
    z0 = fmaf(wq[S][0][0], q[(S)-1][0], z0); z1 = fmaf(wq[S][1][0], q[(S)-1][0], z1); \
    z2 = fmaf(wq[S][2][0], q[(S)-1][0], z2); z3 = fmaf(wq[S][3][0], q[(S)-1][0], z3); \
    z0 = fmaf(wq[S][0][1], q[(S)-1][1], z0); z1 = fmaf(wq[S][1][1], q[(S)-1][1], z1); \
    z2 = fmaf(wq[S][2][1], q[(S)-1][1], z2); z3 = fmaf(wq[S][3][1], q[(S)-1][1], z3); \
    z0 = fmaf(wq[S][0][2], q[(S)-1][2], z0); z1 = fmaf(wq[S][1][2], q[(S)-1][2], z1); \
    z2 = fmaf(wq[S][2][2], q[(S)-1][2], z2); z3 = fmaf(wq[S][3][2], q[(S)-1][2], z3); \
    z0 = fmaf(wq[S][0][3], q[(S)-1][3], z0); z1 = fmaf(wq[S][1][3], q[(S)-1][3], z1); \
    z2 = fmaf(wq[S][2][3], q[(S)-1][3], z2); z3 = fmaf(wq[S][3][3], q[(S)-1][3], z3)

#define STEP(XV) do { \
    float q[7][4]; \
    ROTS(1); ROTS(2); ROTS(3); ROTS(4); ROTS(5); ROTS(6); ROTS(7); \
    PIN8(q[0][0],q[0][1],q[0][2],q[0][3],q[1][0],q[1][1],q[1][2],q[1][3]); \
    PIN8(q[2][0],q[2][1],q[2][2],q[2][3],q[3][0],q[3][1],q[3][2],q[3][3]); \
    PIN8(q[4][0],q[4][1],q[4][2],q[4][3],q[5][0],q[5][1],q[5][2],q[5][3]); \
    PIN4(q[6][0],q[6][1],q[6][2],q[6][3]); \
    float z0 = wih[0] * (XV); \
    float z1 = wih[1] * (XV); \
    float z2 = wih[2] * (XV); \
    float z3 = wih[3] * (XV); \
    /* s = 0: own chunk, multiplicand is h directly */ \
    z0 = fmaf(wq[0][0][0], h0, z0); z1 = fmaf(wq[0][1][0], h0, z1); \
    z2 = fmaf(wq[0][2][0], h0, z2); z3 = fmaf(wq[0][3][0], h0, z3); \
    z0 = fmaf(wq[0][0][1], h1, z0); z1 = fmaf(wq[0][1][1], h1, z1); \
    z2 = fmaf(wq[0][2][1], h1, z2); z3 = fmaf(wq[0][3][1], h1, z3); \
    z0 = fmaf(wq[0][0][2], h2, z0); z1 = fmaf(wq[0][1][2], h2, z1); \
    z2 = fmaf(wq[0][2][2], h2, z2); z3 = fmaf(wq[0][3][2], h2, z3); \
    z0 = fmaf(wq[0][0][3], h3, z0); z1 = fmaf(wq[0][1][3], h3, z1); \
    z2 = fmaf(wq[0][2][3], h3, z2); z3 = fmaf(wq[0][3][3], h3, z3); \
    FMAS(1); FMAS(2); FMAS(3); FMAS(4); FMAS(5); FMAS(6); FMAS(7); \
    h0 = copysignf(fmaxf(fabsf(z0) + bm[0], 0.0f), z0); \
    h1 = copysignf(fmaxf(fabsf(z1) + bm[1], 0.0f), z1); \
    h2 = copysignf(fmaxf(fabsf(z2) + bm[2], 0.0f), z2); \
    h3 = copysignf(fmaxf(fabsf(z3) + bm[3], 0.0f), z3); \
} while (0)

    // ---- main recurrence: 196 outer iters x 4 steps, x double-buffered ----
    const float4* xv4 = (const float4*)(xl + bl * XPAD);
    float4 xq = xv4[0];
    #pragma unroll 1
    for (int m = 0; m < 196; ++m) {
        // force W residency every iteration (0 instructions)
        #pragma unroll
        for (int s = 0; s < 8; ++s) {
            PIN8(wq[s][0][0], wq[s][0][1], wq[s][0][2], wq[s][0][3],
                 wq[s][1][0], wq[s][1][1], wq[s][1][2], wq[s][1][3]);
            PIN8(wq[s][2][0], wq[s][2][1], wq[s][2][2], wq[s][2][3],
                 wq[s][3][0], wq[s][3][1], wq[s][3][2], wq[s][3][3]);
        }
        PIN8(wih[0], wih[1], wih[2], wih[3], bm[0], bm[1], bm[2], bm[3]);

        int mn = m + 1; if (mn > 195) mn = 195;
        float4 xn = xv4[mn];            // ds_read_b128, consumed next iter

        STEP(xq.x);
        STEP(xq.y);
        STEP(xq.z);
        STEP(xq.w);

        xq = xn;
    }
#undef STEP
#undef FMAS
#undef ROTS

    // ---- stash h for classifier ----
    const int r0b = 4 * u;
    hfin[bl * 32 + r0b + 0] = h0;
    hfin[bl * 32 + r0b + 1] = h1;
    hfin[bl * 32 + r0b + 2] = h2;
    hfin[bl * 32 + r0b + 3] = h3;
    __syncthreads();

    // ---- classifier: 80 outputs (8 batches x 10 classes) ----
    #pragma unroll
    for (int it = 0; it < 2; ++it) {
        const int k = l + 64 * it;
        if (k < BPB * NC) {
            const int bbo = k / NC;
            const int c   = k % NC;
            float acc = b_lin[c];
            #pragma unroll
            for (int i = 0; i < NH; ++i) {
                acc = fmaf(W_lin[c * NH + i], hfin[bbo * 32 + i], acc);
            }
            out[((size_t)blk * BPB + bbo) * NC + c] = acc;
        }
    }
}

extern "C" void kernel_launch(void* const* d_in, const int* in_sizes, int n_in,
                              void* d_out, int out_size, void* d_ws, size_t ws_size,
                              hipStream_t stream) {
    const float* inp   = (const float*)d_in[0];
    const float* W_ih  = (const float*)d_in[1];
    const float* W_hh  = (const float*)d_in[2];
    const float* b_mod = (const float*)d_in[3];
    const float* W_lin = (const float*)d_in[4];
    const float* b_lin = (const float*)d_in[5];
    float* out = (float*)d_out;

    dim3 grid(NBATCH / BPB);   // 1024 blocks
    dim3 block(64);            // one wave
    rnn_modrelu_l8<<<grid, block, 0, stream>>>(inp, W_ih, W_hh, b_mod,
                                               W_lin, b_lin, out);
}

// Round 2
// 298.281 us; speedup vs baseline: 1.0280x; 1.0280x over previous
//
#include <hip/hip_runtime.h>

// expRNN/modReLU recurrence, B=8192, T=784, I=1, H=30, C=10.
//
// Round 7: R6 post-mortem showed unroll x4 + DPP clustering cut stall
// 165->122 cyc/step, but the in-loop "+v" pins added ~193 busy cyc/step of
// AGPR<->VGPR shuttle movs (W lives in AGPRs; VGPR_Count 104 is arch-VGPRs
// only, and gfx950 VALU reads AGPRs penalty-free - R5's 2cyc/fma fit).
// => R7 = R6 minus ALL in-loop pins (W and q). Keep: unroll x4, float4
// x double-buffer (1 ds_read_b128 per 4 steps, consumed next iter),
// clustered 28-DPP block per step, pre-loop pins only.
// Predict: busy ~410 cyc/step, stall ~120 -> ~530 cyc/step ~= 200 us,
// VALUBusy 76-80%, VGPR ~104.

#define T_STEPS 784
#define NBATCH  8192
#define NH      30
#define NC      10
#define BPB     8     // batches per block
#define XPAD    788   // padded x row: 788%4==0 (float4 LDS) and
                      // 788%32==20 -> 8 batch rows hit distinct banks

// lane receives value from lane (w - 2S) & 15 within its 16-lane row
#define ROR2(dst, src, S) \
    dst = __int_as_float(__builtin_amdgcn_update_dpp( \
        0, __float_as_int(src), 0x120 + 2*(S), 0xf, 0xf, true))

#define PIN8(a,b,c,d,e,f,g,h) \
    asm volatile("" : "+v"(a),"+v"(b),"+v"(c),"+v"(d), \
                      "+v"(e),"+v"(f),"+v"(g),"+v"(h))

__global__ __launch_bounds__(64, 1)
void rnn_modrelu_l8(const float* __restrict__ inp,    // [B, T, 1]
                    const float* __restrict__ W_ih,   // [H, 1]
                    const float* __restrict__ W_hh,   // [H, H]
                    const float* __restrict__ b_mod,  // [H]
                    const float* __restrict__ W_lin,  // [C, H]
                    const float* __restrict__ b_lin,  // [C]
                    float* __restrict__ out)          // [B, C]
{
    __shared__ __align__(16) float xl[BPB * XPAD];   // 25.2 KB
    __shared__ __align__(16) float wl[NH * NH];      // 3.6 KB
    __shared__ float hfin[BPB * 32];

    const int l     = threadIdx.x;
    const int blk   = blockIdx.x;
    const int w16   = l & 15;
    const int row16 = l >> 4;
    const int u     = w16 >> 1;          // 8-lane sub-index (chunk owner)
    const int bl    = 2 * row16 + (w16 & 1);  // local batch 0..7

    // ---- preload x (8 batches x 784), padded rows, coalesced float4 ----
    {
        const float4* src = (const float4*)(inp + (size_t)blk * (BPB * T_STEPS));
        #pragma unroll
        for (int k = 0; k < 25; ++k) {
            int v = l + 64 * k;                 // float4 index, < 1568
            if (v < (BPB * T_STEPS) / 4) {
                int b   = v / 196;              // 196 float4 per batch row
                int rem = v - b * 196;
                *(float4*)(xl + b * XPAD + 4 * rem) = src[v];
            }
        }
    }
    // ---- stage W_hh to LDS (coalesced) ----
    {
        const float4* src = (const float4*)W_hh;
        #pragma unroll
        for (int k = 0; k < 4; ++k) {
            int idx = l + 64 * k;
            if (idx < (NH * NH) / 4) ((float4*)wl)[idx] = src[idx];
        }
    }
    __syncthreads();

    // ---- per-lane pre-rotated W: step s consumes chunk c=(u-s)&7 ----
    const int r0 = 4 * u;                // first owned row
    float wq[8][4][4];
    #pragma unroll
    for (int s = 0; s < 8; ++s) {
        const int c = (u - s) & 7;
        #pragma unroll
        for (int r = 0; r < 4; ++r) {
            const int row = r0 + r;
            #pragma unroll
            for (int j = 0; j < 4; ++j) {
                const int col = 4 * c + j;
                wq[s][r][j] = (row < NH && col < NH) ? wl[row * NH + col] : 0.0f;
            }
        }
    }
    float wih[4], bm[4];
    #pragma unroll
    for (int r = 0; r < 4; ++r) {
        const int row = r0 + r;
        wih[r] = (row < NH) ? W_ih[row]  : 0.0f;
        bm[r]  = (row < NH) ? b_mod[row] : 0.0f;
    }
    // pin W once (pre-loop only; in-loop pins forced AGPR<->VGPR shuttles)
    #pragma unroll
    for (int s = 0; s < 8; ++s) {
        PIN8(wq[s][0][0], wq[s][0][1], wq[s][0][2], wq[s][0][3],
             wq[s][1][0], wq[s][1][1], wq[s][1][2], wq[s][1][3]);
        PIN8(wq[s][2][0], wq[s][2][1], wq[s][2][2], wq[s][2][3],
             wq[s][3][0], wq[s][3][1], wq[s][3][2], wq[s][3][3]);
    }

    float h0 = 0.0f, h1 = 0.0f, h2 = 0.0f, h3 = 0.0f;  // own rows r0..r0+3

// one recurrence step; all 28 DPP rotations clustered up front (no pins)
#define ROTS(S) ROR2(q[(S)-1][0], h0, S); ROR2(q[(S)-1][1], h1, S); \
                ROR2(q[(S)-1][2], h2, S); ROR2(q[(S)-1][3], h3, S)
#define FMAS(S) \
    z0 = fmaf(wq[S][0][0], q[(S)-1][0], z0); z1 = fmaf(wq[S][1][0], q[(S)-1][0], z1); \
    z2 = fmaf(wq[S][2][0], q[(S)-1][0], z2); z3 = fmaf(wq[S][3][0], q[(S)-1][0], z3); \
    z0 = fmaf(wq[S][0][1], q[(S)-1][1], z0); z1 = fmaf(wq[S][1][1], q[(S)-1][1], z1); \
    z2 = fmaf(wq[S][2][1], q[(S)-1][1], z2); z3 = fmaf(wq[S][3][1], q[(S)-1][1], z3); \
    z0 = fmaf(wq[S][0][2], q[(S)-1][2], z0); z1 = fmaf(wq[S][1][2], q[(S)-1][2], z1); \
    z2 = fmaf(wq[S][2][2], q[(S)-1][2], z2); z3 = fmaf(wq[S][3][2], q[(S)-1][2], z3); \
    z0 = fmaf(wq[S][0][3], q[(S)-1][3], z0); z1 = fmaf(wq[S][1][3], q[(S)-1][3], z1); \
    z2 = fmaf(wq[S][2][3], q[(S)-1][3], z2); z3 = fmaf(wq[S][3][3], q[(S)-1][3], z3)

#define STEP(XV) do { \
    float q[7][4]; \
    ROTS(1); ROTS(2); ROTS(3); ROTS(4); ROTS(5); ROTS(6); ROTS(7); \
    float z0 = wih[0] * (XV); \
    float z1 = wih[1] * (XV); \
    float z2 = wih[2] * (XV); \
    float z3 = wih[3] * (XV); \
    /* s = 0: own chunk, multiplicand is h directly */ \
    z0 = fmaf(wq[0][0][0], h0, z0); z1 = fmaf(wq[0][1][0], h0, z1); \
    z2 = fmaf(wq[0][2][0], h0, z2); z3 = fmaf(wq[0][3][0], h0, z3); \
    z0 = fmaf(wq[0][0][1], h1, z0); z1 = fmaf(wq[0][1][1], h1, z1); \
    z2 = fmaf(wq[0][2][1], h1, z2); z3 = fmaf(wq[0][3][1], h1, z3); \
    z0 = fmaf(wq[0][0][2], h2, z0); z1 = fmaf(wq[0][1][2], h2, z1); \
    z2 = fmaf(wq[0][2][2], h2, z2); z3 = fmaf(wq[0][3][2], h2, z3); \
    z0 = fmaf(wq[0][0][3], h3, z0); z1 = fmaf(wq[0][1][3], h3, z1); \
    z2 = fmaf(wq[0][2][3], h3, z2); z3 = fmaf(wq[0][3][3], h3, z3); \
    FMAS(1); FMAS(2); FMAS(3); FMAS(4); FMAS(5); FMAS(6); FMAS(7); \
    h0 = copysignf(fmaxf(fabsf(z0) + bm[0], 0.0f), z0); \
    h1 = copysignf(fmaxf(fabsf(z1) + bm[1], 0.0f), z1); \
    h2 = copysignf(fmaxf(fabsf(z2) + bm[2], 0.0f), z2); \
    h3 = copysignf(fmaxf(fabsf(z3) + bm[3], 0.0f), z3); \
} while (0)

    // ---- main recurrence: 196 outer iters x 4 steps, x double-buffered ----
    const float4* xv4 = (const float4*)(xl + bl * XPAD);
    float4 xq = xv4[0];
    #pragma unroll 1
    for (int m = 0; m < 196; ++m) {
        // m+1==196 reads floats 784..787 of the padded row: in-bounds,
        // value discarded after the last iteration.
        float4 xn = xv4[m + 1];          // ds_read_b128, consumed next iter

        STEP(xq.x);
        STEP(xq.y);
        STEP(xq.z);
        STEP(xq.w);

        xq = xn;
    }
#undef STEP
#undef FMAS
#undef ROTS

    // ---- stash h for classifier ----
    hfin[bl * 32 + r0 + 0] = h0;
    hfin[bl * 32 + r0 + 1] = h1;
    hfin[bl * 32 + r0 + 2] = h2;
    hfin[bl * 32 + r0 + 3] = h3;
    __syncthreads();

    // ---- classifier: 80 outputs (8 batches x 10 classes) ----
    #pragma unroll
    for (int it = 0; it < 2; ++it) {
        const int k = l + 64 * it;
        if (k < BPB * NC) {
            const int bbo = k / NC;
            const int c   = k % NC;
            float acc = b_lin[c];
            #pragma unroll
            for (int i = 0; i < NH; ++i) {
                acc = fmaf(W_lin[c * NH + i], hfin[bbo * 32 + i], acc);
            }
            out[((size_t)blk * BPB + bbo) * NC + c] = acc;
        }
    }
}

extern "C" void kernel_launch(void* const* d_in, const int* in_sizes, int n_in,
                              void* d_out, int out_size, void* d_ws, size_t ws_size,
                              hipStream_t stream) {
    const float* inp   = (const float*)d_in[0];
    const float* W_ih  = (const float*)d_in[1];
    const float* W_hh  = (const float*)d_in[2];
    const float* b_mod = (const float*)d_in[3];
    const float* W_lin = (const float*)d_in[4];
    const float* b_lin = (const float*)d_in[5];
    float* out = (float*)d_out;

    dim3 grid(NBATCH / BPB);   // 1024 blocks
    dim3 block(64);            // one wave
    rnn_modrelu_l8<<<grid, block, 0, stream>>>(inp, W_ih, W_hh, b_mod,
                                               W_lin, b_lin, out);
}